// Round 2
// baseline (22.003 us; speedup 1.0000x reference)
//
#include <hip/hip_runtime.h>
#include <hip/hip_bf16.h>
#include <stdint.h>
#include <math.h>

// Nucleus sampling reduces to row-wise max+argmax:
// the top-p filter never removes the row max (mask is shifted right by one,
// so the first sorted element always survives; stable argsort preserves
// first-occurrence on ties). So output = (argmax(logits,-1), max(logits,-1)).
//
// Output buffer layout (read back as float32 by the harness):
//   d_out[0 .. S-1]   = tokens (exact integer values stored as float)
//   d_out[S .. 2S-1]  = scores (float)

#define BLOCK 512

__global__ __launch_bounds__(BLOCK) void rowmax_argmax_kernel(
    const float* __restrict__ logits, float* __restrict__ out, int S, int V) {
    const int row = blockIdx.x;
    const float* rp = logits + (size_t)row * (size_t)V;

    // Alignment peel: number of leading elements until 16B-aligned.
    int head = (int)(((16u - ((uintptr_t)rp & 15u)) & 15u) >> 2);
    if (head > V) head = V;
    const int nvec = (V - head) >> 2;
    const int tail_start = head + (nvec << 2);
    const int ntail = V - tail_start;

    const int tid = threadIdx.x;

    float best = -INFINITY;
    int bidx = 0x7fffffff;

    // Head (indices 0..head-1, the smallest indices — processed first so
    // strict '>' later keeps first occurrence).
    if (tid < head) {
        best = rp[tid];
        bidx = tid;
    }

    // Vectorized body: each thread visits strictly increasing indices, so
    // strict '>' preserves first-occurrence tie semantics within a thread.
    const float4* __restrict__ vp = (const float4*)(rp + head);
    for (int i = tid; i < nvec; i += BLOCK) {
        const float4 v = vp[i];
        const int base = head + (i << 2);
        if (v.x > best) { best = v.x; bidx = base; }
        if (v.y > best) { best = v.y; bidx = base + 1; }
        if (v.z > best) { best = v.z; bidx = base + 2; }
        if (v.w > best) { best = v.w; bidx = base + 3; }
    }

    // Tail (largest indices, processed last — strict '>' keeps earlier).
    if (tid < ntail) {
        const float v = rp[tail_start + tid];
        if (v > best) { best = v; bidx = tail_start + tid; }
    }

    // Wave (64-lane) reduction: take (greater val) or (equal val, lower idx).
    #pragma unroll
    for (int off = 32; off >= 1; off >>= 1) {
        const float ov = __shfl_down(best, off, 64);
        const int   oi = __shfl_down(bidx, off, 64);
        if (ov > best || (ov == best && oi < bidx)) { best = ov; bidx = oi; }
    }

    // Cross-wave reduction via LDS (BLOCK/64 waves).
    __shared__ float s_val[BLOCK / 64];
    __shared__ int   s_idx[BLOCK / 64];
    const int wave = tid >> 6;
    const int lane = tid & 63;
    if (lane == 0) { s_val[wave] = best; s_idx[wave] = bidx; }
    __syncthreads();

    if (tid == 0) {
        float fb = s_val[0];
        int fi = s_idx[0];
        #pragma unroll
        for (int w = 1; w < BLOCK / 64; ++w) {
            const float ov = s_val[w];
            const int   oi = s_idx[w];
            if (ov > fb || (ov == fb && oi < fi)) { fb = ov; fi = oi; }
        }
        out[row]     = (float)fi;  // token index, exactly representable (< 2^24)
        out[S + row] = fb;         // score
    }
}

extern "C" void kernel_launch(void* const* d_in, const int* in_sizes, int n_in,
                              void* d_out, int out_size, void* d_ws, size_t ws_size,
                              hipStream_t stream) {
    const float* logits = (const float*)d_in[0];
    float* out = (float*)d_out;

    const int S = out_size / 2;              // 512 rows (tokens + scores)
    const int V = in_sizes[0] / S;           // 50257 vocab

    rowmax_argmax_kernel<<<S, BLOCK, 0, stream>>>(logits, out, S, V);
}